// Round 1
// baseline (689.923 us; speedup 1.0000x reference)
//
#include <hip/hip_runtime.h>

#define BATCH 4096
#define NAG   8
#define OBS   64
#define HD    64
#define GH    128
#define NACT  16

// ============================================================ helpers
__device__ __forceinline__ float fast_sigmoid(float x) {
    // v_exp_f32-based; ~few-ulp error -> gate-flip probability ~1e-2 total
    return 1.f / (1.f + __expf(-x));
}
__device__ __forceinline__ float fast_tanh(float x) {
    x = fminf(fmaxf(x, -15.f), 15.f);      // avoid inf/inf
    const float e = __expf(2.f * x);
    return (e - 1.f) / (e + 1.f);
}

// ============================================================ A: encode
// h[b,n,:] = relu(relu(obs[b,n,:] @ W1[n] + b1[n]) @ W2[n] + b2[n])
// grid: 8 agents x 16 batch-tiles, 256 thr; one thread per (b,n) row.
// Weight addresses are wave-uniform (agent from blockIdx) -> scalar loads.
__global__ __launch_bounds__(256) void encode_kernel(
    const float* __restrict__ obs, const float* __restrict__ W1,
    const float* __restrict__ b1, const float* __restrict__ W2,
    const float* __restrict__ b2, float* __restrict__ h)
{
    const int n = blockIdx.x >> 4;
    const int b = (blockIdx.x & 15) * 256 + threadIdx.x;

    const float* __restrict__ W1n = W1 + n * (OBS * GH);
    const float* __restrict__ W2n = W2 + n * (GH * HD);
    const float* __restrict__ b1n = b1 + n * GH;
    const float* __restrict__ b2n = b2 + n * HD;

    float x[OBS];
    {
        const float* op = obs + (b * NAG + n) * OBS;
#pragma unroll
        for (int o4 = 0; o4 < OBS / 4; ++o4) {
            const float4 v = *reinterpret_cast<const float4*>(op + o4 * 4);
            x[o4*4+0] = v.x; x[o4*4+1] = v.y; x[o4*4+2] = v.z; x[o4*4+3] = v.w;
        }
    }
    float out[HD];
#pragma unroll
    for (int a4 = 0; a4 < HD / 4; ++a4) {
        const float4 v = *reinterpret_cast<const float4*>(b2n + a4 * 4);
        out[a4*4+0] = v.x; out[a4*4+1] = v.y; out[a4*4+2] = v.z; out[a4*4+3] = v.w;
    }

    // interleaved: compute 4 hidden units (h1 quad), immediately fold into out[]
    for (int kq = 0; kq < GH / 4; ++kq) {
        const float4 bq = *reinterpret_cast<const float4*>(b1n + kq * 4);
        float hq[4] = {bq.x, bq.y, bq.z, bq.w};
#pragma unroll
        for (int o = 0; o < OBS; ++o) {
            const float4 wv = *reinterpret_cast<const float4*>(W1n + o * GH + kq * 4);
            hq[0] += x[o] * wv.x; hq[1] += x[o] * wv.y;
            hq[2] += x[o] * wv.z; hq[3] += x[o] * wv.w;
        }
#pragma unroll
        for (int t = 0; t < 4; ++t) {
            const float hv = fmaxf(hq[t], 0.f);
            const float* w2r = W2n + (kq * 4 + t) * HD;
#pragma unroll
            for (int a4 = 0; a4 < HD / 4; ++a4) {
                const float4 wv = *reinterpret_cast<const float4*>(w2r + a4 * 4);
                out[a4*4+0] += hv * wv.x; out[a4*4+1] += hv * wv.y;
                out[a4*4+2] += hv * wv.z; out[a4*4+3] += hv * wv.w;
            }
        }
    }
    float* hp = h + (b * NAG + n) * HD;
#pragma unroll
    for (int a4 = 0; a4 < HD / 4; ++a4) {
        float4 v;
        v.x = fmaxf(out[a4*4+0], 0.f); v.y = fmaxf(out[a4*4+1], 0.f);
        v.z = fmaxf(out[a4*4+2], 0.f); v.w = fmaxf(out[a4*4+3], 0.f);
        *reinterpret_cast<float4*>(hp + a4 * 4) = v;
    }
}

// ============================================================ B: pairwise GRU + hard gate
// For off-diagonal pair (i,j), batch tile of 64:
//   gates[b,g] = [h_i(b);h_j(b)] . Wi[i,j,g,:]  (GEMM M=64,N=384,K=128)
//   GRU epilogue -> g_c;  margin = sum_c g_c*(Wg1-Wg0)[c] + dbg + dgum
//   w[b,i,j] = margin > 0
// Gates reindexed g' = 3c+s so each thread holds (r,z,n) triples locally.
// Thread tile: 4 batch x 8 channels (24 gate accumulators x4 batch = 96 acc).
#define TB 64          // batch tile
#define KC 16          // K chunk staged in LDS
#define UPAD 68        // u_lds row stride (16B-aligned, conflict-light)

__global__ __launch_bounds__(256) void pair_kernel(
    const float* __restrict__ h, const float* __restrict__ Wi,
    const float* __restrict__ bi, const float* __restrict__ bh,
    const float* __restrict__ Wg, const float* __restrict__ bg,
    const float* __restrict__ gum, float* __restrict__ wout)
{
    const int pairp = blockIdx.x >> 6;     // 0..55 (off-diagonal only)
    const int tile  = blockIdx.x & 63;
    const int i = pairp / 7;
    int j = pairp % 7; j += (j >= i);
    const int b0 = tile * TB;
    const int pb = i * NAG + j;

    __shared__ float u_lds[GH * UPAD];     // [k][batch], 34816 B
    __shared__ float w_lds[KC * 384];      // [k][gate'], 24576 B
    __shared__ float part[TB * 17];        // logit partials [b][cg], 4352 B

    const int tid = threadIdx.x;

    // ---- stage u = [h_i ; h_j] transposed to [k][batch] ----
    {
        const int c  = tid & 63;
        const int r0 = tid >> 6;           // 0..3
        for (int rr = 0; rr < 16; ++rr) {
            const int bb = r0 + rr * 4;
            const int b  = b0 + bb;
            u_lds[c * UPAD + bb]        = h[(b * NAG + i) * HD + c];
            u_lds[(64 + c) * UPAD + bb] = h[(b * NAG + j) * HD + c];
        }
    }

    const int bq = tid & 15;               // batch quad: rows bq*4..+3
    const int cg = tid >> 4;               // channel group: c = cg*8..+7

    float acc[3][8][4];                    // [s][cc][bb]
#pragma unroll
    for (int s = 0; s < 3; ++s)
#pragma unroll
        for (int cc = 0; cc < 8; ++cc)
#pragma unroll
            for (int bb = 0; bb < 4; ++bb) acc[s][cc][bb] = 0.f;

    const float* __restrict__ Wp = Wi + (size_t)pb * (384 * GH);

    for (int kc = 0; kc < GH / KC; ++kc) {
        __syncthreads();                   // u ready (kc=0) / w_lds free (kc>0)
        // ---- stage W chunk, reindexing gate g=s*128+c -> g'=3c+s ----
        {
            const int k4 = tid & 3;        // which float4 along k
            const int gl = tid >> 2;       // 0..63
#pragma unroll
            for (int pp = 0; pp < 6; ++pp) {
                const int g = pp * 64 + gl;
                const int s = g >> 7, c = g & 127;
                const int gp = 3 * c + s;
                const float4 v = *reinterpret_cast<const float4*>(
                    Wp + g * GH + kc * KC + k4 * 4);
                w_lds[(k4*4+0) * 384 + gp] = v.x;
                w_lds[(k4*4+1) * 384 + gp] = v.y;
                w_lds[(k4*4+2) * 384 + gp] = v.z;
                w_lds[(k4*4+3) * 384 + gp] = v.w;
            }
        }
        __syncthreads();
        // ---- GEMM inner: outer product over k ----
#pragma unroll 2
        for (int k = 0; k < KC; ++k) {
            const float4 uu = *reinterpret_cast<const float4*>(
                &u_lds[(kc * KC + k) * UPAD + bq * 4]);
            const float ub[4] = {uu.x, uu.y, uu.z, uu.w};
            float wv[24];
#pragma unroll
            for (int m = 0; m < 6; ++m) {
                const float4 t = *reinterpret_cast<const float4*>(
                    &w_lds[k * 384 + cg * 24 + m * 4]);
                wv[m*4+0] = t.x; wv[m*4+1] = t.y; wv[m*4+2] = t.z; wv[m*4+3] = t.w;
            }
#pragma unroll
            for (int cc = 0; cc < 8; ++cc)
#pragma unroll
                for (int s = 0; s < 3; ++s) {
                    const float w0 = wv[cc * 3 + s];
#pragma unroll
                    for (int bb = 0; bb < 4; ++bb)
                        acc[s][cc][bb] += w0 * ub[bb];
                }
        }
    }

    // ---- GRU epilogue + gate-head partial dot ----
    float plog[4] = {0.f, 0.f, 0.f, 0.f};
    const float* __restrict__ bip = bi + pb * 384;
    const float* __restrict__ bhp = bh + pb * 384;
    const float* __restrict__ wgp = Wg + pb * 256;
#pragma unroll
    for (int cc = 0; cc < 8; ++cc) {
        const int c = cg * 8 + cc;
        const float bir = bip[c], biz = bip[128 + c], bin = bip[256 + c];
        const float bhr = bhp[c], bhz = bhp[128 + c], bhn = bhp[256 + c];
        const float dwg = wgp[128 + c] - wgp[c];
#pragma unroll
        for (int bb = 0; bb < 4; ++bb) {
            const float r  = fast_sigmoid(acc[0][cc][bb] + bir + bhr);
            const float z  = fast_sigmoid(acc[1][cc][bb] + biz + bhz);
            const float nn = fast_tanh(acc[2][cc][bb] + bin + r * bhn);
            plog[bb] += (1.f - z) * nn * dwg;
        }
    }
#pragma unroll
    for (int bb = 0; bb < 4; ++bb)
        part[(bq * 4 + bb) * 17 + cg] = plog[bb];
    __syncthreads();

    // ---- deterministic reduce over 16 channel groups + hard decision ----
    if (tid < TB) {
        float s = 0.f;
#pragma unroll
        for (int t = 0; t < 16; ++t) s += part[tid * 17 + t];
        const int b = b0 + tid;
        const float dbg = bg[pb * 2 + 1] - bg[pb * 2 + 0];
        const float* gp2 = gum + ((size_t)(b * NAG + i) * NAG + j) * 2;
        const float margin = s + dbg + (gp2[1] - gp2[0]);
        wout[(b * NAG + i) * NAG + j] = (margin > 0.f) ? 1.f : 0.f;
    }
}

// ============================================================ C: aggregate + decode
// other[b,i] = sum_{j!=i} w[b,i,j] * h[b,j];  q = [h_i;other] @ Wd[i]^T + bd
// grid: 256 blocks x 128 thr; block = 16 batch rows, thread = (bb, i).
__global__ __launch_bounds__(128) void agg_kernel(
    const float* __restrict__ h, const float* __restrict__ w,
    const float* __restrict__ Wd, const float* __restrict__ bd,
    float* __restrict__ q)
{
    const int b0 = blockIdx.x * 16;
    __shared__ float hl[16 * 520];         // [bb][n*64], padded row
    const int tid = threadIdx.x;
    for (int p = 0; p < 64; ++p) {
        const int idx = p * 128 + tid;     // 0..8191
        const int r = idx >> 9, cc = idx & 511;
        hl[r * 520 + cc] = h[(size_t)b0 * 512 + idx];
    }
    __syncthreads();

    const int bb = tid >> 3, i = tid & 7;
    const int b = b0 + bb;

    float other[HD];
#pragma unroll
    for (int c = 0; c < HD; ++c) other[c] = 0.f;
    for (int j = 0; j < NAG; ++j) {
        if (j == i) continue;
        const float wv = w[(b * NAG + i) * NAG + j];
        const float* hr = &hl[bb * 520 + j * 64];
#pragma unroll
        for (int c4 = 0; c4 < HD / 4; ++c4) {
            const float4 v = *reinterpret_cast<const float4*>(hr + c4 * 4);
            other[c4*4+0] += wv * v.x; other[c4*4+1] += wv * v.y;
            other[c4*4+2] += wv * v.z; other[c4*4+3] += wv * v.w;
        }
    }
    const float* hi = &hl[bb * 520 + i * 64];
    const float* __restrict__ Wdp = Wd + i * (NACT * 2 * HD);
    float* qp = q + ((size_t)b * NAG + i) * NACT;
#pragma unroll
    for (int a = 0; a < NACT; ++a) {
        float acc0 = bd[i * NACT + a];
        const float* wr = Wdp + a * 2 * HD;
#pragma unroll
        for (int c4 = 0; c4 < HD / 4; ++c4) {
            const float4 w1 = *reinterpret_cast<const float4*>(wr + c4 * 4);
            const float4 w2 = *reinterpret_cast<const float4*>(wr + 64 + c4 * 4);
            acc0 += hi[c4*4+0] * w1.x + hi[c4*4+1] * w1.y
                  + hi[c4*4+2] * w1.z + hi[c4*4+3] * w1.w
                  + other[c4*4+0] * w2.x + other[c4*4+1] * w2.y
                  + other[c4*4+2] * w2.z + other[c4*4+3] * w2.w;
        }
        qp[a] = acc0;
    }
}

// ============================================================ launch
extern "C" void kernel_launch(void* const* d_in, const int* in_sizes, int n_in,
                              void* d_out, int out_size, void* d_ws, size_t ws_size,
                              hipStream_t stream) {
    const float* obs = (const float*)d_in[0];
    const float* gum = (const float*)d_in[1];
    const float* W1  = (const float*)d_in[2];
    const float* b1  = (const float*)d_in[3];
    const float* W2  = (const float*)d_in[4];
    const float* b2  = (const float*)d_in[5];
    const float* Wi  = (const float*)d_in[6];
    const float* bi  = (const float*)d_in[7];
    const float* bh  = (const float*)d_in[8];
    const float* Wg  = (const float*)d_in[9];
    const float* bg  = (const float*)d_in[10];
    const float* Wd  = (const float*)d_in[11];
    const float* bd  = (const float*)d_in[12];
    float* q = (float*)d_out;

    float* h = (float*)d_ws;                       // B*8*64 = 2,097,152 f32 (8 MB)
    float* w = h + (size_t)BATCH * NAG * HD;       // B*8*8  =   262,144 f32 (1 MB)

    hipLaunchKernelGGL(encode_kernel, dim3(NAG * (BATCH / 256)), dim3(256), 0, stream,
                       obs, W1, b1, W2, b2, h);
    hipLaunchKernelGGL(pair_kernel, dim3(56 * (BATCH / TB)), dim3(256), 0, stream,
                       h, Wi, bi, bh, Wg, bg, gum, w);
    hipLaunchKernelGGL(agg_kernel, dim3(BATCH / 16), dim3(128), 0, stream,
                       h, w, Wd, bd, q);
}

// Round 3
// 434.322 us; speedup vs baseline: 1.5885x; 1.5885x over previous
//
#include <hip/hip_runtime.h>

#define BATCH 4096
#define NAG   8
#define OBS   64
#define HD    64
#define GH    128
#define NACT  16

// ============================================================ helpers
__device__ __forceinline__ float fast_sigmoid(float x) {
    return 1.f / (1.f + __expf(-x));
}
__device__ __forceinline__ float fast_tanh(float x) {
    x = fminf(fmaxf(x, -15.f), 15.f);      // avoid inf/inf
    const float e = __expf(2.f * x);
    return (e - 1.f) / (e + 1.f);
}

// ============================================================ A: encode (GEMM-tiled)
// h[b,n,:] = relu(relu(obs[b,n,:] @ W1[n] + b1[n]) @ W2[n] + b2[n])
// block = (agent n, 64-batch tile), 256 thr; two register-tiled GEMMs via LDS.
// grid 512 blocks = 2048 waves (8 waves/CU) vs old 512 waves on 128 CUs.
__global__ __launch_bounds__(256, 2) void encode_kernel(
    const float* __restrict__ obs, const float* __restrict__ W1,
    const float* __restrict__ b1, const float* __restrict__ W2,
    const float* __restrict__ b2, float* __restrict__ h)
{
    const int n    = blockIdx.x >> 6;
    const int tile = blockIdx.x & 63;
    const int b0   = tile * 64;
    const int tid  = threadIdx.x;

    __shared__ float u1[OBS * 68];       // obs^T [o][bb], 17408 B
    __shared__ float h1t[GH * 68];       // h1^T  [c][bb], 34816 B
    __shared__ float wl[16 * GH];        // weight K-chunk, 8192 B

    const float* __restrict__ W1n = W1 + n * (OBS * GH);
    const float* __restrict__ W2n = W2 + n * (GH * HD);
    const float* __restrict__ b1n = b1 + n * GH;
    const float* __restrict__ b2n = b2 + n * HD;

    // ---- stage obs^T: lane = channel (coalesced global rows) ----
    {
        const int c  = tid & 63;
        const int r0 = tid >> 6;
        for (int rr = 0; rr < 16; ++rr) {
            const int bb = r0 * 16 + rr;
            u1[c * 68 + bb] = obs[((size_t)(b0 + bb) * NAG + n) * OBS + c];
        }
    }

    const int bq = tid & 15;             // batch quad: rows bq*4..+3
    const int cg = tid >> 4;             // channel group

    // ================= GEMM1: M=64, N=128, K=64 =================
    float acc1[8][4];
#pragma unroll
    for (int cc = 0; cc < 8; ++cc)
#pragma unroll
        for (int bb = 0; bb < 4; ++bb) acc1[cc][bb] = 0.f;

    for (int kc = 0; kc < 4; ++kc) {
        __syncthreads();
        // stage W1 rows kc*16..+15 (2048 f32 = 512 float4, 2/thread)
#pragma unroll
        for (int p = 0; p < 2; ++p) {
            const int f = tid + p * 256;
            const int k = f >> 5, c4 = f & 31;
            *reinterpret_cast<float4*>(&wl[k * GH + c4 * 4]) =
                *reinterpret_cast<const float4*>(&W1n[(kc * 16 + k) * GH + c4 * 4]);
        }
        __syncthreads();
#pragma unroll 2
        for (int k = 0; k < 16; ++k) {
            const float4 uu = *reinterpret_cast<const float4*>(
                &u1[(kc * 16 + k) * 68 + bq * 4]);
            const float ub[4] = {uu.x, uu.y, uu.z, uu.w};
            const float4 wa = *reinterpret_cast<const float4*>(&wl[k * GH + cg * 8]);
            const float4 wb = *reinterpret_cast<const float4*>(&wl[k * GH + cg * 8 + 4]);
            const float wv[8] = {wa.x, wa.y, wa.z, wa.w, wb.x, wb.y, wb.z, wb.w};
#pragma unroll
            for (int cc = 0; cc < 8; ++cc)
#pragma unroll
                for (int bb = 0; bb < 4; ++bb)
                    acc1[cc][bb] += wv[cc] * ub[bb];
        }
    }

    // ---- epilogue1: +b1, relu, write h1^T to LDS ----
    {
        const float4 ba = *reinterpret_cast<const float4*>(&b1n[cg * 8]);
        const float4 bb4 = *reinterpret_cast<const float4*>(&b1n[cg * 8 + 4]);
        const float bv[8] = {ba.x, ba.y, ba.z, ba.w, bb4.x, bb4.y, bb4.z, bb4.w};
#pragma unroll
        for (int cc = 0; cc < 8; ++cc)
#pragma unroll
            for (int bb = 0; bb < 4; ++bb)
                h1t[(cg * 8 + cc) * 68 + bq * 4 + bb] =
                    fmaxf(acc1[cc][bb] + bv[cc], 0.f);
    }

    // ================= GEMM2: M=64, N=64, K=128 =================
    const int og = tid >> 4;             // out-channel group: og*4..+3
    float acc2[4][4];
#pragma unroll
    for (int oc = 0; oc < 4; ++oc)
#pragma unroll
        for (int bb = 0; bb < 4; ++bb) acc2[oc][bb] = 0.f;

    for (int kc = 0; kc < 8; ++kc) {
        __syncthreads();                 // h1t ready (kc=0) / wl free
        // stage W2 rows kc*16..+15 (1024 f32 = 256 float4, 1/thread)
        {
            const int k = tid >> 4, o4 = tid & 15;
            *reinterpret_cast<float4*>(&wl[k * HD + o4 * 4]) =
                *reinterpret_cast<const float4*>(&W2n[(kc * 16 + k) * HD + o4 * 4]);
        }
        __syncthreads();
#pragma unroll 2
        for (int k = 0; k < 16; ++k) {
            const float4 uu = *reinterpret_cast<const float4*>(
                &h1t[(kc * 16 + k) * 68 + bq * 4]);
            const float ub[4] = {uu.x, uu.y, uu.z, uu.w};
            const float4 wa = *reinterpret_cast<const float4*>(&wl[k * HD + og * 4]);
            const float wv[4] = {wa.x, wa.y, wa.z, wa.w};
#pragma unroll
            for (int oc = 0; oc < 4; ++oc)
#pragma unroll
                for (int bb = 0; bb < 4; ++bb)
                    acc2[oc][bb] += wv[oc] * ub[bb];
        }
    }

    // ---- epilogue2: +b2, relu, coalesced float4 store ----
    {
        const float4 b2v = *reinterpret_cast<const float4*>(&b2n[og * 4]);
#pragma unroll
        for (int bb = 0; bb < 4; ++bb) {
            float4 o;
            o.x = fmaxf(acc2[0][bb] + b2v.x, 0.f);
            o.y = fmaxf(acc2[1][bb] + b2v.y, 0.f);
            o.z = fmaxf(acc2[2][bb] + b2v.z, 0.f);
            o.w = fmaxf(acc2[3][bb] + b2v.w, 0.f);
            *reinterpret_cast<float4*>(
                &h[((size_t)(b0 + bq * 4 + bb) * NAG + n) * HD + og * 4]) = o;
        }
    }
}

// ============================================================ B: pairwise GRU + hard gate
// Unchanged math vs R1 (passed, absmax 0.0078). Changes: __launch_bounds__(256,2)
// lifts the 104-VGPR cap (96 accumulators were being shuffled through AGPRs —
// ~108us of extra VALU); w_lds stride 384->388 halves staging write conflicts
// (4*388 mod 32 = 16, so k4-row groups split across 2 bank sets).
#define TB 64
#define KC 16
#define UPAD 68
#define WPAD 388       // 16B-aligned (388*4 = 1552 = 97*16), stride mod 32 = 4

__global__ __launch_bounds__(256, 2) void pair_kernel(
    const float* __restrict__ h, const float* __restrict__ Wi,
    const float* __restrict__ bi, const float* __restrict__ bh,
    const float* __restrict__ Wg, const float* __restrict__ bg,
    const float* __restrict__ gum, float* __restrict__ wout)
{
    const int pairp = blockIdx.x >> 6;     // 0..55 (off-diagonal only)
    const int tile  = blockIdx.x & 63;
    const int i = pairp / 7;
    int j = pairp % 7; j += (j >= i);
    const int b0 = tile * TB;
    const int pb = i * NAG + j;

    __shared__ float u_lds[GH * UPAD];     // [k][batch], 34816 B
    __shared__ float w_lds[KC * WPAD];     // [k][gate'], 24832 B
    __shared__ float part[TB * 17];        // logit partials, 4352 B

    const int tid = threadIdx.x;

    // ---- stage u = [h_i ; h_j] transposed to [k][batch] ----
    {
        const int c  = tid & 63;
        const int r0 = tid >> 6;
        for (int rr = 0; rr < 16; ++rr) {
            const int bb = r0 + rr * 4;
            const int b  = b0 + bb;
            u_lds[c * UPAD + bb]        = h[(b * NAG + i) * HD + c];
            u_lds[(64 + c) * UPAD + bb] = h[(b * NAG + j) * HD + c];
        }
    }

    const int bq = tid & 15;
    const int cg = tid >> 4;

    float acc[3][8][4];
#pragma unroll
    for (int s = 0; s < 3; ++s)
#pragma unroll
        for (int cc = 0; cc < 8; ++cc)
#pragma unroll
            for (int bb = 0; bb < 4; ++bb) acc[s][cc][bb] = 0.f;

    const float* __restrict__ Wp = Wi + (size_t)pb * (384 * GH);

    for (int kc = 0; kc < GH / KC; ++kc) {
        __syncthreads();
        // ---- stage W chunk, reindexing gate g=s*128+c -> g'=3c+s ----
        {
            const int k4 = tid & 3;
            const int gl = tid >> 2;
#pragma unroll
            for (int pp = 0; pp < 6; ++pp) {
                const int g = pp * 64 + gl;
                const int s = g >> 7, c = g & 127;
                const int gp = 3 * c + s;
                const float4 v = *reinterpret_cast<const float4*>(
                    Wp + g * GH + kc * KC + k4 * 4);
                w_lds[(k4*4+0) * WPAD + gp] = v.x;
                w_lds[(k4*4+1) * WPAD + gp] = v.y;
                w_lds[(k4*4+2) * WPAD + gp] = v.z;
                w_lds[(k4*4+3) * WPAD + gp] = v.w;
            }
        }
        __syncthreads();
#pragma unroll 2
        for (int k = 0; k < KC; ++k) {
            const float4 uu = *reinterpret_cast<const float4*>(
                &u_lds[(kc * KC + k) * UPAD + bq * 4]);
            const float ub[4] = {uu.x, uu.y, uu.z, uu.w};
            float wv[24];
#pragma unroll
            for (int m = 0; m < 6; ++m) {
                const float4 t = *reinterpret_cast<const float4*>(
                    &w_lds[k * WPAD + cg * 24 + m * 4]);
                wv[m*4+0] = t.x; wv[m*4+1] = t.y; wv[m*4+2] = t.z; wv[m*4+3] = t.w;
            }
#pragma unroll
            for (int cc = 0; cc < 8; ++cc)
#pragma unroll
                for (int s = 0; s < 3; ++s) {
                    const float w0 = wv[cc * 3 + s];
#pragma unroll
                    for (int bb = 0; bb < 4; ++bb)
                        acc[s][cc][bb] += w0 * ub[bb];
                }
        }
    }

    // ---- GRU epilogue + gate-head partial dot ----
    float plog[4] = {0.f, 0.f, 0.f, 0.f};
    const float* __restrict__ bip = bi + pb * 384;
    const float* __restrict__ bhp = bh + pb * 384;
    const float* __restrict__ wgp = Wg + pb * 256;
#pragma unroll
    for (int cc = 0; cc < 8; ++cc) {
        const int c = cg * 8 + cc;
        const float bir = bip[c], biz = bip[128 + c], bin = bip[256 + c];
        const float bhr = bhp[c], bhz = bhp[128 + c], bhn = bhp[256 + c];
        const float dwg = wgp[128 + c] - wgp[c];
#pragma unroll
        for (int bb = 0; bb < 4; ++bb) {
            const float r  = fast_sigmoid(acc[0][cc][bb] + bir + bhr);
            const float z  = fast_sigmoid(acc[1][cc][bb] + biz + bhz);
            const float nn = fast_tanh(acc[2][cc][bb] + bin + r * bhn);
            plog[bb] += (1.f - z) * nn * dwg;
        }
    }
#pragma unroll
    for (int bb = 0; bb < 4; ++bb)
        part[(bq * 4 + bb) * 17 + cg] = plog[bb];
    __syncthreads();

    // ---- deterministic reduce + hard decision ----
    if (tid < TB) {
        float s = 0.f;
#pragma unroll
        for (int t = 0; t < 16; ++t) s += part[tid * 17 + t];
        const int b = b0 + tid;
        const float dbg = bg[pb * 2 + 1] - bg[pb * 2 + 0];
        const float* gp2 = gum + ((size_t)(b * NAG + i) * NAG + j) * 2;
        const float margin = s + dbg + (gp2[1] - gp2[0]);
        wout[(b * NAG + i) * NAG + j] = (margin > 0.f) ? 1.f : 0.f;
    }
}

// ============================================================ C: aggregate + decode
// thread = (b, i, action-quad): 512 blocks x 256 thr = 2048 waves (was 512).
// "other" recomputed per action-quad (448 FMA) -- cheap vs the occupancy win.
__global__ __launch_bounds__(256, 2) void agg_kernel(
    const float* __restrict__ h, const float* __restrict__ w,
    const float* __restrict__ Wd, const float* __restrict__ bd,
    float* __restrict__ q)
{
    const int b0 = blockIdx.x * 8;
    __shared__ float hl[8 * 520];          // [bb][n*64], 16640 B
    const int tid = threadIdx.x;
#pragma unroll
    for (int p = 0; p < 4; ++p) {
        const int f = tid + p * 256;       // float4 index, 0..1023
        const int r = f >> 7, cc = (f & 127) * 4;
        *reinterpret_cast<float4*>(&hl[r * 520 + cc]) =
            *reinterpret_cast<const float4*>(&h[(size_t)b0 * 512 + f * 4]);
    }
    __syncthreads();

    const int aq = tid & 3;                // action quad: a = aq*4..+3
    const int i  = (tid >> 2) & 7;
    const int bb = tid >> 5;
    const int b  = b0 + bb;

    float other[HD];
#pragma unroll
    for (int c = 0; c < HD; ++c) other[c] = 0.f;
    const float* wrow = w + ((size_t)b * NAG + i) * NAG;
    for (int j = 0; j < NAG; ++j) {
        if (j == i) continue;
        const float wv = wrow[j];
        const float* hr = &hl[bb * 520 + j * 64];
#pragma unroll
        for (int c4 = 0; c4 < HD / 4; ++c4) {
            const float4 v = *reinterpret_cast<const float4*>(hr + c4 * 4);
            other[c4*4+0] += wv * v.x; other[c4*4+1] += wv * v.y;
            other[c4*4+2] += wv * v.z; other[c4*4+3] += wv * v.w;
        }
    }
    const float* hi = &hl[bb * 520 + i * 64];
    const float* __restrict__ Wdp = Wd + (i * NACT) * (2 * HD);
    float qo[4];
#pragma unroll
    for (int t = 0; t < 4; ++t) {
        const int a = aq * 4 + t;
        float acc0 = bd[i * NACT + a];
        const float* wr = Wdp + a * 2 * HD;
#pragma unroll
        for (int c4 = 0; c4 < HD / 4; ++c4) {
            const float4 w1 = *reinterpret_cast<const float4*>(wr + c4 * 4);
            const float4 w2 = *reinterpret_cast<const float4*>(wr + 64 + c4 * 4);
            acc0 += hi[c4*4+0] * w1.x + hi[c4*4+1] * w1.y
                  + hi[c4*4+2] * w1.z + hi[c4*4+3] * w1.w
                  + other[c4*4+0] * w2.x + other[c4*4+1] * w2.y
                  + other[c4*4+2] * w2.z + other[c4*4+3] * w2.w;
        }
        qo[t] = acc0;
    }
    float4 qv = {qo[0], qo[1], qo[2], qo[3]};
    *reinterpret_cast<float4*>(&q[((size_t)b * NAG + i) * NACT + aq * 4]) = qv;
}

// ============================================================ launch
extern "C" void kernel_launch(void* const* d_in, const int* in_sizes, int n_in,
                              void* d_out, int out_size, void* d_ws, size_t ws_size,
                              hipStream_t stream) {
    const float* obs = (const float*)d_in[0];
    const float* gum = (const float*)d_in[1];
    const float* W1  = (const float*)d_in[2];
    const float* b1  = (const float*)d_in[3];
    const float* W2  = (const float*)d_in[4];
    const float* b2  = (const float*)d_in[5];
    const float* Wi  = (const float*)d_in[6];
    const float* bi  = (const float*)d_in[7];
    const float* bh  = (const float*)d_in[8];
    const float* Wg  = (const float*)d_in[9];
    const float* bg  = (const float*)d_in[10];
    const float* Wd  = (const float*)d_in[11];
    const float* bd  = (const float*)d_in[12];
    float* q = (float*)d_out;

    float* h = (float*)d_ws;                       // 8 MB
    float* w = h + (size_t)BATCH * NAG * HD;       // 1 MB

    hipLaunchKernelGGL(encode_kernel, dim3(NAG * (BATCH / 64)), dim3(256), 0, stream,
                       obs, W1, b1, W2, b2, h);
    hipLaunchKernelGGL(pair_kernel, dim3(56 * (BATCH / TB)), dim3(256), 0, stream,
                       h, Wi, bi, bh, Wg, bg, gum, w);
    hipLaunchKernelGGL(agg_kernel, dim3(BATCH / 8), dim3(256), 0, stream,
                       h, w, Wd, bd, q);
}

// Round 5
// 404.461 us; speedup vs baseline: 1.7058x; 1.0738x over previous
//
#include <hip/hip_runtime.h>

#define BATCH 4096
#define NAG   8
#define OBS   64
#define HD    64
#define GH    128
#define NACT  16
#define TAU   0.05f
#define CAP   65536

typedef short  bf16x8 __attribute__((ext_vector_type(8)));
typedef unsigned short u16x8 __attribute__((ext_vector_type(8)));
typedef float  f32x4  __attribute__((ext_vector_type(4)));

// ============================================================ helpers
__device__ __forceinline__ float fast_sigmoid(float x) {
    return 1.f / (1.f + __expf(-x));
}
__device__ __forceinline__ float fast_tanh(float x) {
    x = fminf(fmaxf(x, -15.f), 15.f);
    const float e = __expf(2.f * x);
    return (e - 1.f) / (e + 1.f);
}
__device__ __forceinline__ unsigned short f2bf(float f) {   // RNE f32->bf16
    unsigned int u = __builtin_bit_cast(unsigned int, f);
    u = (u + 0x7FFFu + ((u >> 16) & 1u)) >> 16;
    return (unsigned short)u;
}

// ============================================================ counter zero
__global__ void zero_counter(int* c) { if (threadIdx.x == 0) c[0] = 0; }

// ============================================================ Wi -> bf16, gate-permuted
// out gate index g' = cg*48 + s*16 + cl  <- src gate g = s*128 + cg*16 + cl.
// Groups each channel-block's r/z/n into 3 adjacent 16-wide MFMA column-tiles
// so the GRU epilogue is thread-local (D col = lane&15).
__global__ __launch_bounds__(256) void wiconv_kernel(
    const float* __restrict__ Wi, unsigned short* __restrict__ wib)
{
    const int t   = blockIdx.x * 256 + threadIdx.x;   // 0..344063
    const int pp  = t / 6144;                         // 56 off-diag pairs
    const int rem = t - pp * 6144;
    const int gp  = rem >> 4;                         // 0..383
    const int k8  = rem & 15;                         // 8-elem chunk along k
    const int pi  = pp / 7;
    int pj = pp % 7; pj += (pj >= pi);
    const int pb  = pi * NAG + pj;
    const int cg  = gp / 48;
    const int r2  = gp - cg * 48;
    const int s   = r2 >> 4, cl = r2 & 15;
    const int g   = s * GH + cg * 16 + cl;
    const float* src = Wi + ((size_t)pb * 384 + g) * GH + k8 * 8;
    u16x8 o;
#pragma unroll
    for (int e = 0; e < 8; ++e) o[e] = f2bf(src[e]);
    *reinterpret_cast<u16x8*>(wib + ((size_t)pb * 384 + gp) * GH + k8 * 8) = o;
}

// ============================================================ A: encode (+ bf16 mirror)
__global__ __launch_bounds__(256, 2) void encode_kernel(
    const float* __restrict__ obs, const float* __restrict__ W1,
    const float* __restrict__ b1, const float* __restrict__ W2,
    const float* __restrict__ b2, float* __restrict__ h,
    unsigned short* __restrict__ hb)
{
    const int n    = blockIdx.x >> 6;
    const int tile = blockIdx.x & 63;
    const int b0   = tile * 64;
    const int tid  = threadIdx.x;

    __shared__ float u1[OBS * 68];
    __shared__ float h1t[GH * 68];
    __shared__ float wl[16 * GH];

    const float* __restrict__ W1n = W1 + n * (OBS * GH);
    const float* __restrict__ W2n = W2 + n * (GH * HD);
    const float* __restrict__ b1n = b1 + n * GH;
    const float* __restrict__ b2n = b2 + n * HD;

    {
        const int c  = tid & 63;
        const int r0 = tid >> 6;
        for (int rr = 0; rr < 16; ++rr) {
            const int bb = r0 * 16 + rr;
            u1[c * 68 + bb] = obs[((size_t)(b0 + bb) * NAG + n) * OBS + c];
        }
    }

    const int bq = tid & 15;
    const int cg = tid >> 4;

    float acc1[8][4];
#pragma unroll
    for (int cc = 0; cc < 8; ++cc)
#pragma unroll
        for (int bb = 0; bb < 4; ++bb) acc1[cc][bb] = 0.f;

    for (int kc = 0; kc < 4; ++kc) {
        __syncthreads();
#pragma unroll
        for (int p = 0; p < 2; ++p) {
            const int f = tid + p * 256;
            const int k = f >> 5, c4 = f & 31;
            *reinterpret_cast<float4*>(&wl[k * GH + c4 * 4]) =
                *reinterpret_cast<const float4*>(&W1n[(kc * 16 + k) * GH + c4 * 4]);
        }
        __syncthreads();
#pragma unroll 2
        for (int k = 0; k < 16; ++k) {
            const float4 uu = *reinterpret_cast<const float4*>(
                &u1[(kc * 16 + k) * 68 + bq * 4]);
            const float ub[4] = {uu.x, uu.y, uu.z, uu.w};
            const float4 wa = *reinterpret_cast<const float4*>(&wl[k * GH + cg * 8]);
            const float4 wb = *reinterpret_cast<const float4*>(&wl[k * GH + cg * 8 + 4]);
            const float wv[8] = {wa.x, wa.y, wa.z, wa.w, wb.x, wb.y, wb.z, wb.w};
#pragma unroll
            for (int cc = 0; cc < 8; ++cc)
#pragma unroll
                for (int bb = 0; bb < 4; ++bb)
                    acc1[cc][bb] += wv[cc] * ub[bb];
        }
    }

    {
        const float4 ba  = *reinterpret_cast<const float4*>(&b1n[cg * 8]);
        const float4 bb4 = *reinterpret_cast<const float4*>(&b1n[cg * 8 + 4]);
        const float bv[8] = {ba.x, ba.y, ba.z, ba.w, bb4.x, bb4.y, bb4.z, bb4.w};
#pragma unroll
        for (int cc = 0; cc < 8; ++cc)
#pragma unroll
            for (int bb = 0; bb < 4; ++bb)
                h1t[(cg * 8 + cc) * 68 + bq * 4 + bb] =
                    fmaxf(acc1[cc][bb] + bv[cc], 0.f);
    }

    const int og = tid >> 4;
    float acc2[4][4];
#pragma unroll
    for (int oc = 0; oc < 4; ++oc)
#pragma unroll
        for (int bb = 0; bb < 4; ++bb) acc2[oc][bb] = 0.f;

    for (int kc = 0; kc < 8; ++kc) {
        __syncthreads();
        {
            const int k = tid >> 4, o4 = tid & 15;
            *reinterpret_cast<float4*>(&wl[k * HD + o4 * 4]) =
                *reinterpret_cast<const float4*>(&W2n[(kc * 16 + k) * HD + o4 * 4]);
        }
        __syncthreads();
#pragma unroll 2
        for (int k = 0; k < 16; ++k) {
            const float4 uu = *reinterpret_cast<const float4*>(
                &h1t[(kc * 16 + k) * 68 + bq * 4]);
            const float ub[4] = {uu.x, uu.y, uu.z, uu.w};
            const float4 wa = *reinterpret_cast<const float4*>(&wl[k * HD + og * 4]);
            const float wv[4] = {wa.x, wa.y, wa.z, wa.w};
#pragma unroll
            for (int oc = 0; oc < 4; ++oc)
#pragma unroll
                for (int bb = 0; bb < 4; ++bb)
                    acc2[oc][bb] += wv[oc] * ub[bb];
        }
    }

    {
        const float4 b2v = *reinterpret_cast<const float4*>(&b2n[og * 4]);
#pragma unroll
        for (int bb = 0; bb < 4; ++bb) {
            float4 o;
            o.x = fmaxf(acc2[0][bb] + b2v.x, 0.f);
            o.y = fmaxf(acc2[1][bb] + b2v.y, 0.f);
            o.z = fmaxf(acc2[2][bb] + b2v.z, 0.f);
            o.w = fmaxf(acc2[3][bb] + b2v.w, 0.f);
            const size_t row = (size_t)(b0 + bq * 4 + bb) * NAG + n;
            *reinterpret_cast<float4*>(&h[row * HD + og * 4]) = o;
            ushort4 hv;
            hv.x = f2bf(o.x); hv.y = f2bf(o.y); hv.z = f2bf(o.z); hv.w = f2bf(o.w);
            *reinterpret_cast<ushort4*>(&hb[row * HD + og * 4]) = hv;
        }
    }
}

// ============================================================ B: pairwise GRU via MFMA
// block = (pair, 64-batch tile), 4 waves; wave w owns gates g' in [w*96, w*96+96).
// GEMM: D[batch, gate'] = u @ Wi'^T via 16x16x32 bf16 MFMA, fragments loaded
// DIRECTLY from global (no LDS, no barriers until the margin reduce).
// A-frag: lane&15 = batch row, (lane>>4)*8 = k-chunk  -> 16B load from hb.
// B-frag: lane&15 = gate col,  (lane>>4)*8 = k-chunk  -> 16B load from wib.
// Epilogue: gate-triples (r,z,n) are 3 adjacent column-tiles -> thread-local GRU.
// Margin sign decided here; |margin|<TAU appended for exact-f32 refinement.
__global__ __launch_bounds__(256, 2) void pair_mfma_kernel(
    const unsigned short* __restrict__ hb, const unsigned short* __restrict__ wib,
    const float* __restrict__ bi, const float* __restrict__ bh,
    const float* __restrict__ Wg, const float* __restrict__ bg,
    const float* __restrict__ gum, float* __restrict__ wout,
    int* __restrict__ list, int* __restrict__ counter)
{
    const int pairp = blockIdx.x >> 6;
    const int tile  = blockIdx.x & 63;
    const int pi = pairp / 7;
    int pj = pairp % 7; pj += (pj >= pi);
    const int pb = pi * NAG + pj;
    const int b0 = tile * 64;

    const int tid = threadIdx.x;
    const int w   = tid >> 6;          // wave 0..3
    const int l   = tid & 63;
    const int cl  = l & 15;            // A: batch row offset / B,D: column
    const int rg  = l >> 4;            // k-chunk group / D row group

    f32x4 acc[4][6];
#pragma unroll
    for (int bt = 0; bt < 4; ++bt)
#pragma unroll
        for (int t = 0; t < 6; ++t) acc[bt][t] = (f32x4){0.f, 0.f, 0.f, 0.f};

#pragma unroll
    for (int kb = 0; kb < 4; ++kb) {
        const int ag = (kb < 2) ? pi : pj;          // u = [h_i ; h_j]
        const int ch = (kb & 1) * 32 + rg * 8;      // channel chunk within agent
        bf16x8 av[4];
#pragma unroll
        for (int bt = 0; bt < 4; ++bt) {
            const int b = b0 + bt * 16 + cl;
            av[bt] = *reinterpret_cast<const bf16x8*>(
                &hb[((size_t)b * NAG + ag) * HD + ch]);
        }
        const size_t wbase = ((size_t)pb * 384 + w * 96 + cl) * GH + kb * 32 + rg * 8;
#pragma unroll
        for (int t = 0; t < 6; ++t) {
            const bf16x8 bv = *reinterpret_cast<const bf16x8*>(
                &wib[wbase + (size_t)t * 16 * GH]);
#pragma unroll
            for (int bt = 0; bt < 4; ++bt)
                acc[bt][t] = __builtin_amdgcn_mfma_f32_16x16x32_bf16(
                    av[bt], bv, acc[bt][t], 0, 0, 0);
        }
    }

    // ---- GRU epilogue: t = cgl*3 + s; channel c = (2w+cgl)*16 + cl ----
    __shared__ float part[64][68];
    float pl[4][4];
#pragma unroll
    for (int bt = 0; bt < 4; ++bt)
#pragma unroll
        for (int r = 0; r < 4; ++r) pl[bt][r] = 0.f;

#pragma unroll
    for (int cgl = 0; cgl < 2; ++cgl) {
        const int c = (2 * w + cgl) * 16 + cl;
        const float bir = bi[pb * 384 + c];
        const float biz = bi[pb * 384 + 128 + c];
        const float bin = bi[pb * 384 + 256 + c];
        const float bhr = bh[pb * 384 + c];
        const float bhz = bh[pb * 384 + 128 + c];
        const float bhn = bh[pb * 384 + 256 + c];
        const float dwg = Wg[pb * 256 + 128 + c] - Wg[pb * 256 + c];
#pragma unroll
        for (int bt = 0; bt < 4; ++bt)
#pragma unroll
            for (int r = 0; r < 4; ++r) {
                const float rr = fast_sigmoid(acc[bt][cgl * 3 + 0][r] + bir + bhr);
                const float zz = fast_sigmoid(acc[bt][cgl * 3 + 1][r] + biz + bhz);
                const float nn = fast_tanh(acc[bt][cgl * 3 + 2][r] + bin + rr * bhn);
                pl[bt][r] += (1.f - zz) * nn * dwg;
            }
    }
#pragma unroll
    for (int bt = 0; bt < 4; ++bt)
#pragma unroll
        for (int r = 0; r < 4; ++r)
            part[bt * 16 + rg * 4 + r][w * 16 + cl] = pl[bt][r];
    __syncthreads();

    // ---- deterministic margin reduce + decision + boundary append ----
    if (tid < 64) {
        float s = 0.f;
#pragma unroll
        for (int t = 0; t < 64; ++t) s += part[tid][t];
        const int b = b0 + tid;
        const float dbg = bg[pb * 2 + 1] - bg[pb * 2 + 0];
        const float* gp2 = gum + ((size_t)(b * NAG + pi) * NAG + pj) * 2;
        const float margin = s + dbg + (gp2[1] - gp2[0]);
        wout[(b * NAG + pi) * NAG + pj] = (margin > 0.f) ? 1.f : 0.f;
        if (fabsf(margin) < TAU) {
            const int idx = atomicAdd(counter, 1);
            if (idx < CAP) list[idx] = (b << 6) | (pi << 3) | pj;
        }
    }
}

// ============================================================ B2: exact-f32 refinement
// wave-per-boundary-entry; recomputes the margin in f32 (same math as the
// R1/R3 all-f32 kernel) and overwrites the gate bit. ~6K entries expected.
__global__ __launch_bounds__(256) void refine_kernel(
    const float* __restrict__ h, const float* __restrict__ Wi,
    const float* __restrict__ bi, const float* __restrict__ bh,
    const float* __restrict__ Wg, const float* __restrict__ bg,
    const float* __restrict__ gum, const int* __restrict__ list,
    const int* __restrict__ counter, float* __restrict__ wout)
{
    const int l   = threadIdx.x & 63;
    const int wid = (blockIdx.x * 256 + threadIdx.x) >> 6;
    const int nw  = gridDim.x * 4;
    int count = counter[0]; if (count > CAP) count = CAP;

    for (int e = wid; e < count; e += nw) {
        const int code = list[e];
        const int b = code >> 6, pi2 = (code >> 3) & 7, pj2 = code & 7;
        const int pb = pi2 * NAG + pj2;
        const float* hi = h + ((size_t)b * NAG + pi2) * HD;
        const float* hj = h + ((size_t)b * NAG + pj2) * HD;
        const float* Wr = Wi + (size_t)pb * 384 * GH;
        const int c0 = l * 2;

        float a[6] = {0.f, 0.f, 0.f, 0.f, 0.f, 0.f};   // r0,r1,z0,z1,n0,n1
        for (int k4 = 0; k4 < 32; ++k4) {
            const float4 uv = (k4 < 16)
                ? *reinterpret_cast<const float4*>(hi + k4 * 4)
                : *reinterpret_cast<const float4*>(hj + (k4 - 16) * 4);
#pragma unroll
            for (int s = 0; s < 3; ++s)
#pragma unroll
                for (int cc = 0; cc < 2; ++cc) {
                    const float4 wv = *reinterpret_cast<const float4*>(
                        Wr + (size_t)(s * GH + c0 + cc) * GH + k4 * 4);
                    a[s * 2 + cc] += uv.x * wv.x + uv.y * wv.y
                                   + uv.z * wv.z + uv.w * wv.w;
                }
        }
        float pl = 0.f;
#pragma unroll
        for (int cc = 0; cc < 2; ++cc) {
            const int c = c0 + cc;
            const float rr = fast_sigmoid(a[0 + cc] + bi[pb * 384 + c] + bh[pb * 384 + c]);
            const float zz = fast_sigmoid(a[2 + cc] + bi[pb * 384 + 128 + c] + bh[pb * 384 + 128 + c]);
            const float nn = fast_tanh(a[4 + cc] + bi[pb * 384 + 256 + c]
                                       + rr * bh[pb * 384 + 256 + c]);
            pl += (1.f - zz) * nn * (Wg[pb * 256 + 128 + c] - Wg[pb * 256 + c]);
        }
#pragma unroll
        for (int m = 1; m < 64; m <<= 1) pl += __shfl_xor(pl, m, 64);
        if (l == 0) {
            const float dbg = bg[pb * 2 + 1] - bg[pb * 2 + 0];
            const float* gp2 = gum + ((size_t)(b * NAG + pi2) * NAG + pj2) * 2;
            const float margin = pl + dbg + (gp2[1] - gp2[0]);
            wout[(b * NAG + pi2) * NAG + pj2] = (margin > 0.f) ? 1.f : 0.f;
        }
    }
}

// ============================================================ C: aggregate + decode
__global__ __launch_bounds__(256, 2) void agg_kernel(
    const float* __restrict__ h, const float* __restrict__ w,
    const float* __restrict__ Wd, const float* __restrict__ bd,
    float* __restrict__ q)
{
    const int b0 = blockIdx.x * 8;
    __shared__ float hl[8 * 520];
    const int tid = threadIdx.x;
#pragma unroll
    for (int p = 0; p < 4; ++p) {
        const int f = tid + p * 256;
        const int r = f >> 7, cc = (f & 127) * 4;
        *reinterpret_cast<float4*>(&hl[r * 520 + cc]) =
            *reinterpret_cast<const float4*>(&h[(size_t)b0 * 512 + f * 4]);
    }
    __syncthreads();

    const int aq = tid & 3;
    const int i  = (tid >> 2) & 7;
    const int bb = tid >> 5;
    const int b  = b0 + bb;

    float other[HD];
#pragma unroll
    for (int c = 0; c < HD; ++c) other[c] = 0.f;
    const float* wrow = w + ((size_t)b * NAG + i) * NAG;
    for (int j = 0; j < NAG; ++j) {
        if (j == i) continue;
        const float wv = wrow[j];
        const float* hr = &hl[bb * 520 + j * 64];
#pragma unroll
        for (int c4 = 0; c4 < HD / 4; ++c4) {
            const float4 v = *reinterpret_cast<const float4*>(hr + c4 * 4);
            other[c4*4+0] += wv * v.x; other[c4*4+1] += wv * v.y;
            other[c4*4+2] += wv * v.z; other[c4*4+3] += wv * v.w;
        }
    }
    const float* hi = &hl[bb * 520 + i * 64];
    const float* __restrict__ Wdp = Wd + (i * NACT) * (2 * HD);
    float qo[4];
#pragma unroll
    for (int t = 0; t < 4; ++t) {
        const int a = aq * 4 + t;
        float acc0 = bd[i * NACT + a];
        const float* wr = Wdp + a * 2 * HD;
#pragma unroll
        for (int c4 = 0; c4 < HD / 4; ++c4) {
            const float4 w1 = *reinterpret_cast<const float4*>(wr + c4 * 4);
            const float4 w2 = *reinterpret_cast<const float4*>(wr + 64 + c4 * 4);
            acc0 += hi[c4*4+0] * w1.x + hi[c4*4+1] * w1.y
                  + hi[c4*4+2] * w1.z + hi[c4*4+3] * w1.w
                  + other[c4*4+0] * w2.x + other[c4*4+1] * w2.y
                  + other[c4*4+2] * w2.z + other[c4*4+3] * w2.w;
        }
        qo[t] = acc0;
    }
    float4 qv = {qo[0], qo[1], qo[2], qo[3]};
    *reinterpret_cast<float4*>(&q[((size_t)b * NAG + i) * NACT + aq * 4]) = qv;
}

// ============================================================ launch
// ws layout (float units):
//   h      @ 0         (2,097,152 f32, 8 MB)
//   w      @ 2,097,152 (  262,144 f32, 1 MB)
//   hb     @ 2,359,296 (2,097,152 bf16, 4 MB)
//   wib    @ 3,407,872 (3,145,728 bf16, 6 MB, pb-sparse over 64)
//   list   @ 4,980,736 (65,536 int, 256 KB)
//   cnt    @ 5,046,272 (1 int)          total ~20.2 MB of ws
extern "C" void kernel_launch(void* const* d_in, const int* in_sizes, int n_in,
                              void* d_out, int out_size, void* d_ws, size_t ws_size,
                              hipStream_t stream) {
    const float* obs = (const float*)d_in[0];
    const float* gum = (const float*)d_in[1];
    const float* W1  = (const float*)d_in[2];
    const float* b1  = (const float*)d_in[3];
    const float* W2  = (const float*)d_in[4];
    const float* b2  = (const float*)d_in[5];
    const float* Wi  = (const float*)d_in[6];
    const float* bi  = (const float*)d_in[7];
    const float* bh  = (const float*)d_in[8];
    const float* Wg  = (const float*)d_in[9];
    const float* bg  = (const float*)d_in[10];
    const float* Wd  = (const float*)d_in[11];
    const float* bd  = (const float*)d_in[12];
    float* q = (float*)d_out;

    float*          ws   = (float*)d_ws;
    float*          h    = ws;
    float*          w    = ws + 2097152;
    unsigned short* hb   = (unsigned short*)(ws + 2359296);
    unsigned short* wib  = (unsigned short*)(ws + 3407872);
    int*            list = (int*)(ws + 4980736);
    int*            cnt  = (int*)(ws + 5046272);

    hipLaunchKernelGGL(zero_counter, dim3(1), dim3(64), 0, stream, cnt);
    hipLaunchKernelGGL(wiconv_kernel, dim3(1344), dim3(256), 0, stream, Wi, wib);
    hipLaunchKernelGGL(encode_kernel, dim3(NAG * (BATCH / 64)), dim3(256), 0, stream,
                       obs, W1, b1, W2, b2, h, hb);
    hipLaunchKernelGGL(pair_mfma_kernel, dim3(56 * 64), dim3(256), 0, stream,
                       hb, wib, bi, bh, Wg, bg, gum, w, list, cnt);
    hipLaunchKernelGGL(refine_kernel, dim3(256), dim3(256), 0, stream,
                       h, Wi, bi, bh, Wg, bg, gum, list, cnt, w);
    hipLaunchKernelGGL(agg_kernel, dim3(BATCH / 8), dim3(256), 0, stream,
                       h, w, Wd, bd, q);
}